// Round 15
// baseline (41.540 us; speedup 1.0000x reference)
//
#include <hip/hip_runtime.h>

#define NRES  300
#define NTRJ  20
#define NBINS 34
#define PLANE (NTRJ * NRES * 3)      // 18000 floats per output plane
#define IC    2                      // i's per CB block
#define NCH   150                    // 300 / IC
#define NCBB  (5 * NCH)              // 750 CB blocks
#define NHCH  15                     // H j-chunks (20 j each)
#define NHBB  (5 * NHCH)             // 75 H blocks
#define OFF_H (2 * NCH)              // H partial planes at 300..314
#define NPLANES (2 * NCH + NHCH)     // 315 partial planes (22.68 MB)
#define WROWP 36                     // padded floats per w row (16B multiple)
#define NRED  ((PLANE + 255) / 256)  // 71

#define EXP2F(x) __builtin_exp2f(x)
#define LOG2F(x) __builtin_log2f(x)

// One launch, two block ranges:
//  [0, 750): CB distogram + HB O-sum. Lane = (bsub 0..3, jsub 0..15); wave wv
//    owns 16 j rows; b = bsub*5+q register-blocked. Wave-private LDS staging
//    (barrier-free), w rows padded to 36 floats -> 9 ds_read_b128 per lane-i,
//    i-side coords packed [b][ii][8] -> 2 ds_read_b128 per q. NO shuffles,
//    NO atomics: per-chunk partial planes.
//  [750, 825): HB H-sum. Lane = i (64), serial over 20 j; hmin/hmax transposed
//    via padded LDS [20][65]; register accumulation; partials to ws.
template <bool PART>
__global__ __launch_bounds__(256)
void force_fused(const float* __restrict__ cO, const float* __restrict__ cCB,
                 const float* __restrict__ cH, const float* __restrict__ gw,
                 const float* __restrict__ hmin, const float* __restrict__ hmax,
                 float* __restrict__ out, float* __restrict__ part) {
  __shared__ __align__(16) float smem[3800];   // 15.2 KB, carved per part

  const int tid  = threadIdx.x;
  const int wv   = tid >> 6;
  const int lane = tid & 63;

  if (blockIdx.x < NCBB) {
    // ==================== CB + O part ====================
    float* wbufw = smem + wv * (16 * WROWP);       // wave-private w tile
    float* sIC   = smem + 4 * (16 * WROWP);        // [20][IC][8] packed coords

    const int bsub = lane >> 4;
    const int jsub = lane & 15;
    const int jt   = blockIdx.x % 5;
    const int ch   = blockIdx.x / 5;               // 0..NCH-1
    const int i0   = ch * IC;
    const int j0w  = jt * 64 + wv * 16;
    const int j    = j0w + jsub;
    const bool jv  = (j < NRES);
    const int jc   = jv ? j : NRES - 1;
    const int E2   = 17 * min(16, max(0, NRES - j0w));  // valid float2 in tile

    // stage packed i-side coords: [b][ii][ CBx,CBy,CBz,_, Hx,Hy,Hz,_ ]
    for (int e = tid; e < NTRJ * IC * 6; e += 256) {
      const int b = e / (IC * 6), r = e % (IC * 6);
      const int ii = r / 6, c = r % 6;
      const int comp = (c < 3) ? c : c - 3;
      const int src = ((b * NRES) + i0 + ii) * 3 + comp;
      sIC[(b * IC + ii) * 8 + (c < 3 ? c : c + 1)] = (c < 3) ? cCB[src] : cH[src];
    }
    __syncthreads();

    float pjx[5], pjy[5], pjz[5], pox[5], poy[5], poz[5];
    float acx[5] = {}, acy[5] = {}, acz[5] = {};   // accs_CB[b,j]
    float aox[5] = {}, aoy[5] = {}, aoz[5] = {};   // accs_O [b,j]
#pragma unroll
    for (int q = 0; q < 5; ++q) {
      const int b = bsub * 5 + q;
      const float* p = cCB + ((size_t)(b * NRES + jc)) * 3;
      pjx[q] = p[0]; pjy[q] = p[1]; pjz[q] = p[2];
      const float* o = cO + ((size_t)(b * NRES + jc)) * 3;
      pox[q] = o[0]; poy[q] = o[1]; poz[q] = o[2];
    }

    // prefetch wave tile for i0 (contiguous 272 float2 per 16 rows)
    float2 r2[5];
    {
      const float2* src = (const float2*)gw + ((size_t)i0 * NRES + j0w) * 17;
#pragma unroll
      for (int u = 0; u < 5; ++u) {
        const int e = lane + u * 64;
        r2[u] = (e < E2) ? src[e] : make_float2(0.f, 0.f);
      }
    }

    for (int ii = 0; ii < IC; ++ii) {
      const int i = i0 + ii;
      // wave-private stage into padded rows (row*18+col in float2 units);
      // DS pipe is in-order per wave -> no barrier needed
#pragma unroll
      for (int u = 0; u < 5; ++u) {
        const int e = lane + u * 64;
        if (e < 272) {
          const int row = e / 17, col = e - row * 17;
          ((float2*)wbufw)[row * 18 + col] = r2[u];
        }
      }
      if (ii + 1 < IC) {
        const float2* src =
            (const float2*)gw + ((size_t)(i + 1) * NRES + j0w) * 17;
#pragma unroll
        for (int u = 0; u < 5; ++u) {
          const int e = lane + u * 64;
          r2[u] = (e < E2) ? src[e] : make_float2(0.f, 0.f);
        }
      }

      // w: 9 x ds_read_b128 (padded rows; 2-way bank alias = free)
      float w[36];
      {
        const float4* wp = (const float4*)&wbufw[jsub * WROWP];
#pragma unroll
        for (int k4 = 0; k4 < 9; ++k4) {
          float4 v = wp[k4];
          w[4*k4+0] = v.x; w[4*k4+1] = v.y; w[4*k4+2] = v.z; w[4*k4+3] = v.w;
        }
        w[34] = 0.f; w[35] = 0.f;   // padding lanes
      }

      const float hmn = hmin[i * NRES + jc];
      const float hmx = hmax[i * NRES + jc];

#pragma unroll
      for (int q = 0; q < 5; ++q) {
        const int b = bsub * 5 + q;
        const float4* ic4 = (const float4*)&sIC[(b * IC + ii) * 8];
        const float4 cb = ic4[0];
        const float4 hh = ic4[1];

        // ---- CB distogram: 3 x 12-bin exp2 ratio-recurrence chains ----
        float dx = pjx[q] - cb.x, dy = pjy[q] - cb.y, dz = pjz[q] - cb.z;
        float d2 = fmaf(dx, dx, fmaf(dy, dy, dz * dz));
        d2 = fminf(fmaxf(d2, 0.01f), 1600.0f);        // d in [0.1, 40]
        float rinv = __frsqrt_rn(d2);
        float d    = d2 * rinv;
        float dA = d - 3.75f, dB = d - 9.75f, dC = d - 15.75f;
        float gA = EXP2F(-0.46166241f * dA * dA);
        float mA = EXP2F(fmaf(0.46166241f, dA, -0.11541560f));
        float gB = EXP2F(-0.46166241f * dB * dB);
        float mB = EXP2F(fmaf(0.46166241f, dB, -0.11541560f));
        float gC = EXP2F(-0.46166241f * dC * dC);
        float mC = EXP2F(fmaf(0.46166241f, dC, -0.11541560f));
        float s0 = 0.f, s1 = 0.f, s2 = 0.f;
#pragma unroll
        for (int k = 0; k < 12; ++k) {
          s0 = fmaf(w[k]      * dA, gA, s0); gA *= mA; mA *= 0.85214379f; dA -= 0.5f;
          s1 = fmaf(w[k + 12] * dB, gB, s1); gB *= mB; mB *= 0.85214379f; dB -= 0.5f;
          s2 = fmaf(w[k + 24] * dC, gC, s2); gC *= mC; mC *= 0.85214379f; dC -= 0.5f;
        }
        float cf = 76.8f * ((s0 + s1) + s2) * rinv;   // 150 / sigma^3
        acx[q] = fmaf(cf, dx, acx[q]);
        acy[q] = fmaf(cf, dy, acy[q]);
        acz[q] = fmaf(cf, dz, acz[q]);

        // ---- HB restraint (O_j - H_i): accs_O only ----
        float ex = pox[q] - hh.x, ey = poy[q] - hh.y, ez = poz[q] - hh.z;
        float e2 = fmaf(ex, ex, fmaf(ey, ey, ez * ez));
        e2 = fminf(fmaxf(e2, 0.01f), 1600.0f);
        float rh = __frsqrt_rn(e2);
        float dh = e2 * rh;
        float vmin = fmaxf(hmn - dh, 0.0f);
        float vmax = fmaxf(dh - hmx, 0.0f);
        float fmn = 15.0f * vmin;                     // 3*5*v^1
        float fmx = (vmax > 0.0f) ? 5.0f * EXP2F(0.75f * LOG2F(vmax)) : 0.0f;
        float ff = (fmn - fmx) * rh;
        aox[q] = fmaf(ff, ex, aox[q]);
        aoy[q] = fmaf(ff, ey, aoy[q]);
        aoz[q] = fmaf(ff, ez, aoz[q]);
      }
    }

    if (jv) {
      if constexpr (PART) {
        float* pc  = part + (size_t)ch * PLANE;
        float* po2 = part + (size_t)(NCH + ch) * PLANE;
#pragma unroll
        for (int q = 0; q < 5; ++q) {
          const int base = ((bsub * 5 + q) * NRES + j) * 3;
          pc[base + 0]  = acx[q]; pc[base + 1]  = acy[q]; pc[base + 2]  = acz[q];
          po2[base + 0] = aox[q]; po2[base + 1] = aoy[q]; po2[base + 2] = aoz[q];
        }
      } else {
#pragma unroll
        for (int q = 0; q < 5; ++q) {
          const int base = ((bsub * 5 + q) * NRES + j) * 3;
          atomicAdd(&out[3 * PLANE + base + 0], acx[q]);
          atomicAdd(&out[3 * PLANE + base + 1], acy[q]);
          atomicAdd(&out[3 * PLANE + base + 2], acz[q]);
          atomicAdd(&out[2 * PLANE + base + 0], aox[q]);
          atomicAdd(&out[2 * PLANE + base + 1], aoy[q]);
          atomicAdd(&out[2 * PLANE + base + 2], aoz[q]);
        }
      }
    }
  } else {
    // ==================== H part: accs_H[b,i] = -sum_j pair_hb ============
    float* tmn = smem;                 // [20][65] padded transpose
    float* tmx = smem + 1300;
    float* sO  = smem + 2600;          // [20 b][20 jj][3]

    const int bx2 = blockIdx.x - NCBB;
    const int it  = bx2 % 5;
    const int jch = bx2 / 5;           // 0..14
    const int j0  = jch * 20;
    const int i   = it * 64 + lane;
    const bool iv = (i < NRES);
    const int icl = iv ? i : NRES - 1;
    const int b0  = __builtin_amdgcn_readfirstlane(wv) * 5;

    // stage hmin/hmax transposed ([col][row], row padded 65) + O coords
    for (int e = tid; e < 64 * 20; e += 256) {
      const int row = e / 20, col = e - (e / 20) * 20;
      int ig = it * 64 + row; if (ig > NRES - 1) ig = NRES - 1;
      tmn[col * 65 + row] = hmin[ig * NRES + j0 + col];
      tmx[col * 65 + row] = hmax[ig * NRES + j0 + col];
    }
    for (int e = tid; e < NTRJ * 20 * 3; e += 256) {
      const int b = e / 60, r = e % 60;
      sO[e] = cO[((b * NRES) + j0 + r / 3) * 3 + (r % 3)];
    }

    float phx[5], phy[5], phz[5];
    float ahx[5] = {}, ahy[5] = {}, ahz[5] = {};
#pragma unroll
    for (int q = 0; q < 5; ++q) {
      const float* h = cH + ((size_t)((b0 + q) * NRES + icl)) * 3;
      phx[q] = h[0]; phy[q] = h[1]; phz[q] = h[2];
    }
    __syncthreads();

    for (int jj = 0; jj < 20; ++jj) {
      const float hmn = tmn[jj * 65 + lane];
      const float hmx = tmx[jj * 65 + lane];
#pragma unroll
      for (int q = 0; q < 5; ++q) {
        const float* po = &sO[((b0 + q) * 20 + jj) * 3];   // wave-uniform
        float ex = po[0] - phx[q], ey = po[1] - phy[q], ez = po[2] - phz[q];
        float e2 = fmaf(ex, ex, fmaf(ey, ey, ez * ez));
        e2 = fminf(fmaxf(e2, 0.01f), 1600.0f);
        float rh = __frsqrt_rn(e2);
        float dh = e2 * rh;
        float vmin = fmaxf(hmn - dh, 0.0f);
        float vmax = fmaxf(dh - hmx, 0.0f);
        float fmn = 15.0f * vmin;
        float fmx = (vmax > 0.0f) ? 5.0f * EXP2F(0.75f * LOG2F(vmax)) : 0.0f;
        float ff = (fmn - fmx) * rh;
        ahx[q] = fmaf(-ff, ex, ahx[q]);
        ahy[q] = fmaf(-ff, ey, ahy[q]);
        ahz[q] = fmaf(-ff, ez, ahz[q]);
      }
    }
    if (iv) {
      if constexpr (PART) {
        float* hp = part + (size_t)(OFF_H + jch) * PLANE;
#pragma unroll
        for (int q = 0; q < 5; ++q) {
          const int base = ((b0 + q) * NRES + i) * 3;
          hp[base + 0] = ahx[q]; hp[base + 1] = ahy[q]; hp[base + 2] = ahz[q];
        }
      } else {
#pragma unroll
        for (int q = 0; q < 5; ++q) {
          const int base = ((b0 + q) * NRES + i) * 3;
          atomicAdd(&out[4 * PLANE + base + 0], ahx[q]);
          atomicAdd(&out[4 * PLANE + base + 1], ahy[q]);
          atomicAdd(&out[4 * PLANE + base + 2], ahz[q]);
        }
      }
    }
  }
}

// Segmented reduce: segs 0-2 CB (50 planes each), 3-5 O (50), 6 H (15, sole
// writer -> plain store). 5 independent accumulator chains per thread.
__global__ __launch_bounds__(256)
void reduce_seg(const float* __restrict__ part, float* __restrict__ out) {
  const int seg  = blockIdx.x / NRED;
  const int t    = (blockIdx.x % NRED) * 256 + threadIdx.x;
  if (t >= PLANE) return;

  int c0, cnt;
  if (seg < 3)      { c0 = seg * 50;             cnt = 50; }
  else if (seg < 6) { c0 = NCH + (seg - 3) * 50; cnt = 50; }
  else              { c0 = OFF_H;                cnt = NHCH; }

  const float* p = part + t + (size_t)c0 * PLANE;
  float s[5] = {};
  for (int c = 0; c < cnt; c += 5) {
#pragma unroll
    for (int u = 0; u < 5; ++u) s[u] += p[(size_t)(c + u) * PLANE];
  }
  const float tot = ((s[0] + s[1]) + (s[2] + s[3])) + s[4];
  if (seg < 3)      atomicAdd(&out[3 * PLANE + t], tot);
  else if (seg < 6) atomicAdd(&out[2 * PLANE + t], tot);
  else              out[4 * PLANE + t] = tot;
}

extern "C" void kernel_launch(void* const* d_in, const int* in_sizes, int n_in,
                              void* d_out, int out_size, void* d_ws, size_t ws_size,
                              hipStream_t stream) {
  // input order per setup_inputs(): N, C, O, CB, H, gaussian_weights, hb_min, hb_max
  const float* cO  = (const float*)d_in[2];
  const float* cCB = (const float*)d_in[3];
  const float* cH  = (const float*)d_in[4];
  const float* gw  = (const float*)d_in[5];
  const float* hmn = (const float*)d_in[6];
  const float* hmx = (const float*)d_in[7];
  float* out  = (float*)d_out;
  float* part = (float*)d_ws;

  // N and C planes are exactly zero (K_ANG_HB_GEN == 0); memset also zeroes
  // the atomic-accumulated planes. 360 KB -> negligible.
  (void)hipMemsetAsync(out, 0, (size_t)out_size * sizeof(float), stream);

  if (ws_size >= (size_t)NPLANES * PLANE * sizeof(float)) {   // 22.68 MB
    force_fused<true><<<dim3(NCBB + NHBB), dim3(256), 0, stream>>>(
        cO, cCB, cH, gw, hmn, hmx, out, part);
    reduce_seg<<<dim3(7 * NRED), dim3(256), 0, stream>>>(part, out);
  } else {
    force_fused<false><<<dim3(NCBB + NHBB), dim3(256), 0, stream>>>(
        cO, cCB, cH, gw, hmn, hmx, out, nullptr);
  }
}